// Round 3
// baseline (61.953 us; speedup 1.0000x reference)
//
#include <hip/hip_runtime.h>

namespace {

constexpr int NCLS   = 20;
constexpr int NIMG   = 16384;
constexpr int NCELLS = NIMG * 7 * 7;   // 802816
constexpr int TILE   = 64;             // cells per wave-tile
constexpr int NT     = NCELLS / TILE;  // 12544 exactly
constexpr int NB     = 2560;           // resident blocks (10 per CU target)

__device__ __forceinline__ float cell_loss(const float* __restrict__ p,
                                           const float* __restrict__ l) {
  const float l4 = l[4];
  if (!(l4 > 0.0f)) {
    // no-object cell: 0.5 * sum over both conf channels
    float d4 = p[4] - l4;
    float d9 = p[9] - l[9];
    return 0.5f * (d4 * d4 + d9 * d9);
  }
  const float sc = 1.0f / 7.0f;
  // ground-truth corners from label box 0
  float gcx = l[0] * sc, gcy = l[1] * sc, gw = l[2], gh = l[3];
  float gx1 = gcx - 0.5f * gw, gy1 = gcy - 0.5f * gh;
  float gx2 = gcx + 0.5f * gw, gy2 = gcy + 0.5f * gh;
  float a2 = (gx2 - gx1) * (gy2 - gy1);

  float iou0 = 0.0f, iou1 = 0.0f;
#pragma unroll
  for (int b = 0; b < 2; ++b) {
    const float* bp = p + 5 * b;
    float cx = bp[0] * sc, cy = bp[1] * sc, w = bp[2], h = bp[3];
    float x1 = cx - 0.5f * w, y1 = cy - 0.5f * h;
    float x2 = cx + 0.5f * w, y2 = cy + 0.5f * h;
    float ix1 = fmaxf(x1, gx1), iy1 = fmaxf(y1, gy1);
    float ix2 = fminf(x2, gx2), iy2 = fminf(y2, gy2);
    float inter = fmaxf(ix2 - ix1, 0.0f) * fmaxf(iy2 - iy1, 0.0f);
    float a1 = (x2 - x1) * (y2 - y1);
    float v = inter / (a1 + a2 - inter);
    if (b == 0) iou0 = v; else iou1 = v;
  }
  // argmax with tie -> box 0 (jnp.argmax semantics)
  int r = (iou1 > iou0) ? 1 : 0;
  float miou = fmaxf(iou0, iou1);
  const float* rp = p + 5 * r;
  const float* rl = l + 5 * r;

  float dx = rp[0] - rl[0], dy = rp[1] - rl[1];
  float xy = dx * dx + dy * dy;
  float dw = sqrtf(rp[2]) - sqrtf(rl[2]);
  float dh = sqrtf(rp[3]) - sqrtf(rl[3]);
  float wh = dw * dw + dh * dh;
  float dr = rp[4] - miou;            // response conf vs max IoU
  float nr = p[5 * (1 - r) + 4];      // non-responsible conf
  float cls = 0.0f;
#pragma unroll
  for (int c = 0; c < NCLS; ++c) {
    float d = p[10 + c] - l[10 + c];
    cls = fmaf(d, d, cls);
  }
  return 5.0f * (xy + wh) + 2.0f * (dr * dr) + nr * nr + cls;
}

// One wave per workgroup. 15.4 KB LDS -> 10 resident waves/CU, each a fully
// independent load->LDS->compute pipeline (no cross-wave barriers).
__global__ __launch_bounds__(64) void yolo_loss_main(
    const float* __restrict__ preds, const float* __restrict__ labels,
    double* __restrict__ acc) {
  __shared__ float4 s[960];  // [0,480): preds tile, [480,960): labels tile

  const int lane = threadIdx.x;
  float vsum = 0.0f;

  for (int tile = blockIdx.x; tile < NT; tile += NB) {
    const float4* pb = reinterpret_cast<const float4*>(preds) + (size_t)tile * 480;
    const float4* lb = reinterpret_cast<const float4*>(labels) + (size_t)tile * 480;
    // Coalesced staging: lane-stride-1 float4; r = k*64+lane covers both arrays.
#pragma unroll
    for (int k = 0; k < 15; ++k) {
      int r = k * 64 + lane;
      s[r] = (r < 480) ? pb[r] : lb[r - 480];
    }
    __syncthreads();  // 1-wave block: compiles to waitcnt (+trivial barrier)
    const float* p = reinterpret_cast<const float*>(s) + lane * 30;
    const float* l = reinterpret_cast<const float*>(s) + 1920 + lane * 30;
    vsum += cell_loss(p, l);
    __syncthreads();  // LDS reads done before next tile's staging overwrites
  }

  // wave64 reduction, one double atomic per block (2560 total)
#pragma unroll
  for (int off = 32; off > 0; off >>= 1) vsum += __shfl_down(vsum, off);
  if (lane == 0) atomicAdd(acc, (double)vsum);
}

__global__ void yolo_loss_finalize(const double* __restrict__ acc,
                                   float* __restrict__ out) {
  out[0] = (float)(acc[0] * (1.0 / (double)NIMG));
}

}  // namespace

extern "C" void kernel_launch(void* const* d_in, const int* in_sizes, int n_in,
                              void* d_out, int out_size, void* d_ws, size_t ws_size,
                              hipStream_t stream) {
  const float* preds  = (const float*)d_in[0];
  const float* labels = (const float*)d_in[1];
  double* acc = (double*)d_ws;
  // d_ws is poisoned 0xAA once and never re-poisoned: zero it every launch.
  hipMemsetAsync(d_ws, 0, sizeof(double), stream);
  yolo_loss_main<<<NB, TILE, 0, stream>>>(preds, labels, acc);
  yolo_loss_finalize<<<1, 1, 0, stream>>>(acc, (float*)d_out);
}

// Round 4
// 49.673 us; speedup vs baseline: 1.2472x; 1.2472x over previous
//
#include <hip/hip_runtime.h>

namespace {

constexpr int NCLS   = 20;
constexpr int NIMG   = 16384;
constexpr int NCELLS = NIMG * 7 * 7;     // 802816
constexpr int TCELLS = 64;               // cells per tile (one wave)
constexpr int NT     = NCELLS / TCELLS;  // 12544 exactly
constexpr int NB     = 1280;             // 5 blocks/CU (LDS-limited)
constexpr int TBYTES = TCELLS * 30 * 4;  // 7680 B per array per tile
// LDS: 2 buffers x (preds 7680 + labels 7680) = 30720 B
constexpr int BUF_FLOATS = 2 * 1920;     // floats per buffer (both arrays)

__device__ __forceinline__ float cell_loss(const float* __restrict__ p,
                                           const float* __restrict__ l) {
  const float l4 = l[4];
  if (!(l4 > 0.0f)) {
    float d4 = p[4] - l4;
    float d9 = p[9] - l[9];
    return 0.5f * (d4 * d4 + d9 * d9);
  }
  const float sc = 1.0f / 7.0f;
  float gcx = l[0] * sc, gcy = l[1] * sc, gw = l[2], gh = l[3];
  float gx1 = gcx - 0.5f * gw, gy1 = gcy - 0.5f * gh;
  float gx2 = gcx + 0.5f * gw, gy2 = gcy + 0.5f * gh;
  float a2 = (gx2 - gx1) * (gy2 - gy1);

  float iou0 = 0.0f, iou1 = 0.0f;
#pragma unroll
  for (int b = 0; b < 2; ++b) {
    const float* bp = p + 5 * b;
    float cx = bp[0] * sc, cy = bp[1] * sc, w = bp[2], h = bp[3];
    float x1 = cx - 0.5f * w, y1 = cy - 0.5f * h;
    float x2 = cx + 0.5f * w, y2 = cy + 0.5f * h;
    float ix1 = fmaxf(x1, gx1), iy1 = fmaxf(y1, gy1);
    float ix2 = fminf(x2, gx2), iy2 = fminf(y2, gy2);
    float inter = fmaxf(ix2 - ix1, 0.0f) * fmaxf(iy2 - iy1, 0.0f);
    float a1 = (x2 - x1) * (y2 - y1);
    float v = inter / (a1 + a2 - inter);
    if (b == 0) iou0 = v; else iou1 = v;
  }
  int r = (iou1 > iou0) ? 1 : 0;          // argmax tie -> box 0
  float miou = fmaxf(iou0, iou1);
  const float* rp = p + 5 * r;
  const float* rl = l + 5 * r;

  float dx = rp[0] - rl[0], dy = rp[1] - rl[1];
  float xy = dx * dx + dy * dy;
  float dw = sqrtf(rp[2]) - sqrtf(rl[2]);
  float dh = sqrtf(rp[3]) - sqrtf(rl[3]);
  float wh = dw * dw + dh * dh;
  float dr = rp[4] - miou;
  float nr = p[5 * (1 - r) + 4];
  float cls = 0.0f;
#pragma unroll
  for (int c = 0; c < NCLS; ++c) {
    float d = p[10 + c] - l[10 + c];
    cls = fmaf(d, d, cls);
  }
  return 5.0f * (xy + wh) + 2.0f * (dr * dr) + nr * nr + cls;
}

// One wave per block; double-buffered global_load_lds pipeline with counted
// vmcnt so next-tile HBM loads stay in flight across current-tile compute.
__global__ __launch_bounds__(64) void yolo_loss_main(
    const float* __restrict__ preds, const float* __restrict__ labels,
    double* __restrict__ acc) {
  __shared__ float s[2 * BUF_FLOATS];  // 30720 B

  const int lane = threadIdx.x;

  // Stage one tile (both arrays) into buffer `buf` via direct HBM->LDS DMA.
  // LDS dest is wave-uniform base + lane*size (m104); global src is per-lane.
  auto stage = [&](int tile, int buf) {
    const char* gp = (const char*)preds + (size_t)tile * TBYTES;
    const char* gl = (const char*)labels + (size_t)tile * TBYTES;
    char* lp = (char*)(s + buf * BUF_FLOATS);
    char* ll = lp + TBYTES;
#pragma unroll
    for (int c = 0; c < 7; ++c) {  // 7 x 1KB chunks (lane*16B)
      __builtin_amdgcn_global_load_lds(
          (__attribute__((address_space(1))) const void*)(gp + c * 1024 + lane * 16),
          (__attribute__((address_space(3))) void*)(lp + c * 1024), 16, 0, 0);
      __builtin_amdgcn_global_load_lds(
          (__attribute__((address_space(1))) const void*)(gl + c * 1024 + lane * 16),
          (__attribute__((address_space(3))) void*)(ll + c * 1024), 16, 0, 0);
    }
#pragma unroll
    for (int c = 0; c < 2; ++c) {  // 512B tail: 2 x 256B chunks (lane*4B)
      __builtin_amdgcn_global_load_lds(
          (__attribute__((address_space(1))) const void*)(gp + 7168 + c * 256 + lane * 4),
          (__attribute__((address_space(3))) void*)(lp + 7168 + c * 256), 4, 0, 0);
      __builtin_amdgcn_global_load_lds(
          (__attribute__((address_space(1))) const void*)(gl + 7168 + c * 256 + lane * 4),
          (__attribute__((address_space(3))) void*)(ll + 7168 + c * 256), 4, 0, 0);
    }
  };

  float vsum = 0.0f;
  int buf = 0;
  stage(blockIdx.x, 0);  // prologue: tile 0 of this block

  for (int tile = blockIdx.x; tile < NT; tile += NB) {
    const int next = tile + NB;
    if (next < NT) {
      stage(next, buf ^ 1);  // 18 loads in flight across this tile's compute
      asm volatile("s_waitcnt vmcnt(18)" ::: "memory");  // current tile ready
    } else {
      asm volatile("s_waitcnt vmcnt(0)" ::: "memory");   // drain last tile
    }
    __builtin_amdgcn_sched_barrier(0);  // rule #18: pin reads after the wait

    const float* p = s + buf * BUF_FLOATS + lane * 30;
    const float* l = p + 1920;
    vsum += cell_loss(p, l);

    // Reads of this buffer must complete before its DMA overwrite (2 tiles on).
    asm volatile("s_waitcnt lgkmcnt(0)" ::: "memory");
    buf ^= 1;
  }

  // wave64 reduction, one double atomic per block (1280 total)
#pragma unroll
  for (int off = 32; off > 0; off >>= 1) vsum += __shfl_down(vsum, off);
  if (lane == 0) atomicAdd(acc, (double)vsum);
}

__global__ void yolo_loss_finalize(const double* __restrict__ acc,
                                   float* __restrict__ out) {
  out[0] = (float)(acc[0] * (1.0 / (double)NIMG));
}

}  // namespace

extern "C" void kernel_launch(void* const* d_in, const int* in_sizes, int n_in,
                              void* d_out, int out_size, void* d_ws, size_t ws_size,
                              hipStream_t stream) {
  const float* preds  = (const float*)d_in[0];
  const float* labels = (const float*)d_in[1];
  double* acc = (double*)d_ws;
  // d_ws is poisoned 0xAA once and never re-poisoned: zero it every launch.
  hipMemsetAsync(d_ws, 0, sizeof(double), stream);
  yolo_loss_main<<<NB, TCELLS, 0, stream>>>(preds, labels, acc);
  yolo_loss_finalize<<<1, 1, 0, stream>>>(acc, (float*)d_out);
}